// Round 7
// baseline (505.387 us; speedup 1.0000x reference)
//
#include <hip/hip_runtime.h>
#include <hip/hip_bf16.h>
#include <math.h>

// Problem constants
#define Ln     35
#define CINn   21
#define CINP   24        // padded CIN (multiple of 8 -> aligned b128 im2col reads)
#define Fn     128
#define Kn     9
#define Hn     64
#define GB     8         // batch rows per block (N-dim = 8 batches x 2 l-positions)
#define SEQ_STRIDE 1064  // 44 rows*24 + 8 slack; l=35 window ends exactly at 1064.
                         // word-stride 532 = 20 mod 32 -> full 32-bank tiling, 2-way free
#define TILE_STRIDE 136  // 128 + 8 pad

typedef __attribute__((ext_vector_type(8))) short short8;
typedef __attribute__((ext_vector_type(4))) float f32x4;

static __device__ __forceinline__ unsigned short bf16bits(float f) {
    __hip_bfloat16 h = __float2bfloat16(f);
    return *(unsigned short*)&h;
}

// ---------------- single fused kernel: 8 batch rows / block ----------------
// LDS 30208 B -> 5 blocks/CU by LDS; ~116 VGPR -> 4 blocks/CU (16 waves).
// R4 lesson: do NOT force min-waves (spills weight frags); natural alloc is fine.
__global__ __launch_bounds__(256) void fused_kernel(
    const float* __restrict__ seq,    const int*   __restrict__ plen_arr,
    const float* __restrict__ conv_w, const float* __restrict__ conv_b,
    const float* __restrict__ n_w1,   const float* __restrict__ n_b1,
    const float* __restrict__ n_w2,   const float* __restrict__ n_b2,
    const float* __restrict__ c_w1,   const float* __restrict__ c_b1,
    const float* __restrict__ c_w2,   const float* __restrict__ c_b2,
    const float* __restrict__ navg_w, const float* __restrict__ navg_b,
    const float* __restrict__ cavg_w, const float* __restrict__ cavg_b,
    const float* __restrict__ out_w,  const float* __restrict__ out_b,
    float* __restrict__ out)
{
    __shared__ __align__(16) unsigned short s_seq[GB * SEQ_STRIDE];      // 17024 B
    __shared__ __align__(16) unsigned short s_tile[2][16 * TILE_STRIDE]; // 8704 B
    __shared__ __align__(16) float s_yp[Ln][4][GB];                      // 4480 B
    // overlays on s_seq (dead after the l-loop):
    float* s_y   = (float*)s_seq;            // [2][GB][36] = 576 floats
    float* s_avg = (float*)s_seq + 576;      // [4 waves][2][GB] = 64 floats

    const int t    = threadIdx.x;
    const int wave = t >> 6;
    const int lane = t & 63;
    const int quad = lane >> 4;
    const int col  = lane & 15;
    const int b0   = blockIdx.x * GB;
    const int batch_lane = col & 7;          // conv N-column -> batch
    const int lgrp = col >> 3;               // conv N-column -> l-offset (0/1)

    // ---- zero-init padded seq (pad rows/channels + slack must be 0) ----
    {
        uint4* p = (uint4*)s_seq;                    // 17024/16 = 1064 uint4
        for (int i = t; i < (GB * SEQ_STRIDE) / 8; i += 256)
            p[i] = make_uint4(0u, 0u, 0u, 0u);
    }

    // ---- per-lane loop-invariant weight fragments, gathered in-kernel ----
    // conv A-frag (operand-swapped GEMM): A[m=f=16*tile+col][k=kk], kk'=k*24+c
    // MLP  B-frag: B[k=f][n=ng]
    short8 wb[2][7];
    short8 w1b[2][4];
    float  cbias[2][4], b1v[2], w2v[2];
    const int head = wave >> 1;            // 0 = n-head (waves 0,1), 1 = c (waves 2,3)
    #pragma unroll
    for (int tt = 0; tt < 2; tt++) {
        const int ng = (2 * wave + tt) * 16 + col;   // conv f (A m-index) AND mlp n-index
        #pragma unroll
        for (int s = 0; s < 7; s++) {
            short8 v;
            #pragma unroll
            for (int j = 0; j < 8; j++) {
                int kk = 32 * s + quad * 8 + j;
                int k = kk / CINP, c = kk % CINP;
                float f = (k < Kn && c < CINn) ? conv_w[(k * CINn + c) * Fn + ng] : 0.0f;
                v[j] = (short)bf16bits(f);
            }
            wb[tt][s] = v;
        }
        const int nl = ng & 63;
        #pragma unroll
        for (int s = 0; s < 4; s++) {
            short8 v;
            #pragma unroll
            for (int j = 0; j < 8; j++) {
                int k = 32 * s + quad * 8 + j;
                float f = head ? c_w1[k * Hn + nl] : n_w1[k * Hn + nl];
                v[j] = (short)bf16bits(f);
            }
            w1b[tt][s] = v;
        }
        #pragma unroll
        for (int r = 0; r < 4; r++)
            cbias[tt][r] = conv_b[(2 * wave + tt) * 16 + 4 * quad + r];
        b1v[tt] = head ? c_b1[nl] : n_b1[nl];
        w2v[tt] = head ? c_w2[nl] : n_w2[nl];
    }
    const int plen_lane = plen_arr[b0 + batch_lane];

    __syncthreads();   // zero-init done before data fill

    // ---- stage seq -> bf16 LDS, rows shifted +4 (SAME pad), c<21 only ----
    for (int i = t; i < GB * Ln * CINn; i += 256) {
        int bi = i / (Ln * CINn), r = i % (Ln * CINn);
        int l = r / CINn, c = r % CINn;
        s_seq[bi * SEQ_STRIDE + (4 + l) * CINP + c] =
            bf16bits(seq[(size_t)(b0 + bi) * (Ln * CINn) + r]);
    }
    __syncthreads();

    float sum_n[2][4] = {{0.f,0.f,0.f,0.f},{0.f,0.f,0.f,0.f}};
    float sum_c[2][4] = {{0.f,0.f,0.f,0.f},{0.f,0.f,0.f,0.f}};

    // ---- main loop: one MFMA tile = (8 batches x 2 l). 18 iters, 1 barrier each.
    // 2-slot tile ring: iter i writes slot i&1, barriers, reads it; WAR on the
    // other slot (read in iter i-1) is fenced by iter i's barrier.
    // l=35 is a pad column: computed, auto-masked from sums, y-write guarded.
    for (int l0 = 0; l0 < 36; l0 += 2) {
        const int ln  = l0 + lgrp;              // this lane's conv l-column
        const int slot = (l0 >> 1) & 1;
        // ---- conv GEMM (operand-swapped): D^T[f][(batch,l)] ----
        short8 af[7];
        #pragma unroll
        for (int s = 0; s < 7; s++)
            af[s] = *(const short8*)&s_seq[batch_lane * SEQ_STRIDE + ln * CINP + 32 * s + quad * 8];
        f32x4 cacc[2] = {{0.f,0.f,0.f,0.f},{0.f,0.f,0.f,0.f}};
        #pragma unroll
        for (int s = 0; s < 7; s++) {
            cacc[0] = __builtin_amdgcn_mfma_f32_16x16x32_bf16(wb[0][s], af[s], cacc[0], 0, 0, 0);
            cacc[1] = __builtin_amdgcn_mfma_f32_16x16x32_bf16(wb[1][s], af[s], cacc[1], 0, 0, 0);
        }
        // ---- epilogue: lane holds n=(batch_lane, ln), f = 16*(2w+tt)+4q+r ----
        {
            float nm = (ln < 10) ? 1.0f : 0.0f;
            float cm = (ln >= 10 + plen_lane && ln < 20 + plen_lane) ? 1.0f : 0.0f;
            #pragma unroll
            for (int tt = 0; tt < 2; tt++) {
                float v0 = fmaxf(cacc[tt][0] + cbias[tt][0], 0.0f);
                float v1 = fmaxf(cacc[tt][1] + cbias[tt][1], 0.0f);
                float v2 = fmaxf(cacc[tt][2] + cbias[tt][2], 0.0f);
                float v3 = fmaxf(cacc[tt][3] + cbias[tt][3], 0.0f);
                sum_n[tt][0] += nm * v0; sum_n[tt][1] += nm * v1;
                sum_n[tt][2] += nm * v2; sum_n[tt][3] += nm * v3;
                sum_c[tt][0] += cm * v0; sum_c[tt][1] += cm * v1;
                sum_c[tt][2] += cm * v2; sum_c[tt][3] += cm * v3;
                ushort4 pk = { bf16bits(v0), bf16bits(v1), bf16bits(v2), bf16bits(v3) };
                *(ushort4*)&s_tile[slot][col * TILE_STRIDE + (2 * wave + tt) * 16 + 4 * quad] = pk;
            }
        }
        __syncthreads();   // conv tile written -> MLP may read

        // ---- MLP layer1 GEMM: D[m=(batch,l)][n=h(2 heads)], K = 128 f ----
        short8 am[4];
        #pragma unroll
        for (int s = 0; s < 4; s++)
            am[s] = *(const short8*)&s_tile[slot][col * TILE_STRIDE + 32 * s + quad * 8];
        f32x4 hacc[2] = {{0.f,0.f,0.f,0.f},{0.f,0.f,0.f,0.f}};
        #pragma unroll
        for (int s = 0; s < 4; s++) {
            hacc[0] = __builtin_amdgcn_mfma_f32_16x16x32_bf16(am[s], w1b[0][s], hacc[0], 0, 0, 0);
            hacc[1] = __builtin_amdgcn_mfma_f32_16x16x32_bf16(am[s], w1b[1][s], hacc[1], 0, 0, 0);
        }
        // ---- y = relu(h+b1) @ w2 : per-lane partial, reduce h over 16 cols ----
        float p[4];
        #pragma unroll
        for (int r = 0; r < 4; r++)
            p[r] = fmaxf(hacc[0][r] + b1v[0], 0.f) * w2v[0]
                 + fmaxf(hacc[1][r] + b1v[1], 0.f) * w2v[1];
        #pragma unroll
        for (int r = 0; r < 4; r++) {
            p[r] += __shfl_xor(p[r], 1);
            p[r] += __shfl_xor(p[r], 2);
            p[r] += __shfl_xor(p[r], 4);
            p[r] += __shfl_xor(p[r], 8);
        }
        if (col == 0) {
            // m = quad*4+r -> batch = 4*(quad&1)+r, l = l0 + (quad>>1)
            int lm = l0 + (quad >> 1);
            if (lm < Ln)
                *(f32x4*)&s_yp[lm][wave][(quad & 1) * 4] = (f32x4){p[0], p[1], p[2], p[3]};
        }
    }
    __syncthreads();   // all s_seq reads done -> overlay safe; s_yp complete

    // ---- flank-average partials: apply weights, reduce f (quads) + l-group ----
    {
        float an = 0.f, ac = 0.f;
        #pragma unroll
        for (int tt = 0; tt < 2; tt++)
            #pragma unroll
            for (int r = 0; r < 4; r++) {
                int fidx = (2 * wave + tt) * 16 + 4 * quad + r;
                an += sum_n[tt][r] * navg_w[fidx];
                ac += sum_c[tt][r] * cavg_w[fidx];
            }
        an += __shfl_xor(an, 16); an += __shfl_xor(an, 32); an += __shfl_xor(an, 8);
        ac += __shfl_xor(ac, 16); ac += __shfl_xor(ac, 32); ac += __shfl_xor(ac, 8);
        if (lane < GB) {                     // one lane per batch
            s_avg[wave * 2 * GB + 0 * GB + lane] = an;
            s_avg[wave * 2 * GB + 1 * GB + lane] = ac;
        }
    }
    __syncthreads();

    // ---- y finalize: y = tanh(partial_w0 + partial_w1 + b2), 560 values ----
    {
        const float bn = n_b2[0], bc = c_b2[0];
        for (int i = t; i < 2 * GB * Ln; i += 256) {
            int hd = i / (GB * Ln), rem = i % (GB * Ln);
            int m = rem / Ln, l = rem % Ln;
            float v = s_yp[l][hd * 2][m] + s_yp[l][hd * 2 + 1][m] + (hd ? bc : bn);
            s_y[hd * GB * 36 + m * 36 + l] = tanhf(v);
        }
    }
    __syncthreads();

    // ---- final combine: one thread per batch row ----
    if (t < GB) {
        const int m = t;
        const int plen = plen_arr[b0 + m];
        const float* ym = s_y + m * 36;               // n-head row
        const float* yc = s_y + GB * 36 + m * 36;     // c-head row
        float cleaved_n = ym[10];
        float mn = 0.f;   // reference maxes (y+1)*mask over ALL l; unmasked give 0
        for (int l = 11; l < 10 + plen; l++) mn = fmaxf(mn, ym[l] + 1.f);
        float maxpool_n = -(mn - 1.f);
        float cleaved_c = yc[10 + plen - 1];
        float mc = 0.f;
        for (int l = 10; l < 10 + plen - 1; l++) mc = fmaxf(mc, yc[l] + 1.f);
        float maxpool_c = -(mc - 1.f);
        float sn = 0.f, sc = 0.f;
        #pragma unroll
        for (int w = 0; w < 4; w++) {
            sn += s_avg[w * 2 * GB + 0 * GB + m];
            sc += s_avg[w * 2 * GB + 1 * GB + m];
        }
        float avg_n = tanhf(sn * 0.1f + navg_b[0]);
        float avg_c = tanhf(sc * 0.1f + cavg_b[0]);
        float comb = cleaved_n * out_w[0] + maxpool_n * out_w[1] + avg_n * out_w[2]
                   + cleaved_c * out_w[3] + maxpool_c * out_w[4] + avg_c * out_w[5]
                   + out_b[0];
        out[b0 + m] = 1.f / (1.f + expf(-comb));
    }
}

extern "C" void kernel_launch(void* const* d_in, const int* in_sizes, int n_in,
                              void* d_out, int out_size, void* d_ws, size_t ws_size,
                              hipStream_t stream) {
    const int B = in_sizes[1];
    fused_kernel<<<B / GB, 256, 0, stream>>>(
        (const float*)d_in[0],  (const int*)d_in[1],
        (const float*)d_in[2],  (const float*)d_in[3],
        (const float*)d_in[4],  (const float*)d_in[5],
        (const float*)d_in[6],  (const float*)d_in[7],
        (const float*)d_in[8],  (const float*)d_in[9],
        (const float*)d_in[10], (const float*)d_in[11],
        (const float*)d_in[12], (const float*)d_in[13],
        (const float*)d_in[14], (const float*)d_in[15],
        (const float*)d_in[16], (const float*)d_in[17],
        (float*)d_out);
}

// Round 9
// 419.997 us; speedup vs baseline: 1.2033x; 1.2033x over previous
//
#include <hip/hip_runtime.h>
#include <hip/hip_bf16.h>
#include <math.h>

// Problem constants
#define Ln     35
#define CINn   21
#define CINP   24        // padded CIN (multiple of 8 -> aligned b128 im2col reads)
#define Fn     128
#define Kn     9
#define Hn     64
#define GB     16        // batch rows per block
#define SEQ_STRIDE 1064  // 44 rows*24 + 8 slack; l=35 window ends exactly at 1064
#define TILE_STRIDE 136  // 128 + 8 pad

typedef __attribute__((ext_vector_type(8))) short short8;
typedef __attribute__((ext_vector_type(4))) float f32x4;

static __device__ __forceinline__ unsigned short bf16bits(float f) {
    __hip_bfloat16 h = __float2bfloat16(f);
    return *(unsigned short*)&h;
}

// ---------------- single fused kernel: 16 batch rows / block ----------------
// Software-pipelined: stage i runs conv(l-pair i) AND mlp(l-pair i-1) inside one
// barrier interval -> the two halves' ds_reads and MFMA chains interleave.
// R8 bug: each slot holds TWO 16-row tiles (l0 at rows 0..15, l1 at rows 16..31)
// -> slot size must be 32*TILE_STRIDE (R8 declared 16 -> OOB corruption).
__global__ __launch_bounds__(256, 2) void fused_kernel(
    const float* __restrict__ seq,    const int*   __restrict__ plen_arr,
    const float* __restrict__ conv_w, const float* __restrict__ conv_b,
    const float* __restrict__ n_w1,   const float* __restrict__ n_b1,
    const float* __restrict__ n_w2,   const float* __restrict__ n_b2,
    const float* __restrict__ c_w1,   const float* __restrict__ c_b1,
    const float* __restrict__ c_w2,   const float* __restrict__ c_b2,
    const float* __restrict__ navg_w, const float* __restrict__ navg_b,
    const float* __restrict__ cavg_w, const float* __restrict__ cavg_b,
    const float* __restrict__ out_w,  const float* __restrict__ out_b,
    float* __restrict__ out)
{
    __shared__ __align__(16) unsigned short s_seq[GB * SEQ_STRIDE];       // 34048 B
    __shared__ __align__(16) unsigned short s_tile[2][32 * TILE_STRIDE];  // 17408 B
    __shared__ __align__(16) float s_yp[Ln][4][GB];                       // 8960 B
    // overlays on s_seq (dead after the main loop):
    float* s_y   = (float*)s_seq;            // [2][GB][36] = 1152 floats
    float* s_avg = (float*)s_seq + 1152;     // [4 waves][2][GB] = 128 floats

    const int t    = threadIdx.x;
    const int wave = t >> 6;
    const int lane = t & 63;
    const int quad = lane >> 4;
    const int col  = lane & 15;
    const int b0   = blockIdx.x * GB;

    // ---- zero-init padded seq (pad rows/channels + slack must be 0) ----
    {
        uint4* p = (uint4*)s_seq;
        for (int i = t; i < (GB * SEQ_STRIDE) / 8; i += 256)
            p[i] = make_uint4(0u, 0u, 0u, 0u);
    }

    // ---- per-lane loop-invariant weight fragments, gathered in-kernel ----
    short8 wb[2][7];                       // conv A-frags (operand-swapped)
    short8 w1b[2][4];                      // MLP B-frags
    float  cbias[2][4], b1v[2], w2v[2];
    const int head = wave >> 1;            // 0 = n-head (waves 0,1), 1 = c (waves 2,3)
    #pragma unroll
    for (int tt = 0; tt < 2; tt++) {
        const int ng = (2 * wave + tt) * 16 + col;   // conv f (A m-index) AND mlp n-index
        #pragma unroll
        for (int s = 0; s < 7; s++) {
            short8 v;
            #pragma unroll
            for (int j = 0; j < 8; j++) {
                int kk = 32 * s + quad * 8 + j;
                int k = kk / CINP, c = kk % CINP;
                float f = (k < Kn && c < CINn) ? conv_w[(k * CINn + c) * Fn + ng] : 0.0f;
                v[j] = (short)bf16bits(f);
            }
            wb[tt][s] = v;
        }
        const int nl = ng & 63;
        #pragma unroll
        for (int s = 0; s < 4; s++) {
            short8 v;
            #pragma unroll
            for (int j = 0; j < 8; j++) {
                int k = 32 * s + quad * 8 + j;
                float f = head ? c_w1[k * Hn + nl] : n_w1[k * Hn + nl];
                v[j] = (short)bf16bits(f);
            }
            w1b[tt][s] = v;
        }
        #pragma unroll
        for (int r = 0; r < 4; r++)
            cbias[tt][r] = conv_b[(2 * wave + tt) * 16 + 4 * quad + r];
        b1v[tt] = head ? c_b1[nl] : n_b1[nl];
        w2v[tt] = head ? c_w2[nl] : n_w2[nl];
    }
    const int plen_lane = plen_arr[b0 + col];   // this lane's batch (=col) plen

    __syncthreads();   // zero-init done before data fill

    // ---- stage seq -> bf16 LDS, rows shifted +4 (SAME pad), c<21 only ----
    for (int i = t; i < GB * Ln * CINn; i += 256) {
        int bi = i / (Ln * CINn), r = i % (Ln * CINn);
        int l = r / CINn, c = r % CINn;
        s_seq[bi * SEQ_STRIDE + (4 + l) * CINP + c] =
            bf16bits(seq[(size_t)(b0 + bi) * (Ln * CINn) + r]);
    }
    __syncthreads();

    float sum_n[2][4] = {{0.f,0.f,0.f,0.f},{0.f,0.f,0.f,0.f}};
    float sum_c[2][4] = {{0.f,0.f,0.f,0.f},{0.f,0.f,0.f,0.f}};

    // ---- pipelined main loop: 19 stages; conv at stages 0..17, mlp at 1..18.
    // l-pairs: conv pair i covers l = {2i, 2i+1}; l=35 is a computed pad column
    // (auto-masked from sums; y-write guarded).
    for (int i = 0; i <= 18; i++) {
        const int doConv = (i < 18);
        const int doMlp  = (i > 0);
        const int ws_    = i & 1;          // write slot (conv)
        const int rs_    = 1 - ws_;        // read slot (mlp, pair i-1)

        // ---- issue MLP A-frag reads first (mlp runs first below) ----
        short8 am0[4], am1[4];
        if (doMlp) {
            #pragma unroll
            for (int s = 0; s < 4; s++) {
                am0[s] = *(const short8*)&s_tile[rs_][col * TILE_STRIDE + 32 * s + quad * 8];
                am1[s] = *(const short8*)&s_tile[rs_][(16 + col) * TILE_STRIDE + 32 * s + quad * 8];
            }
        }
        // ---- issue conv B-frag reads (latency hidden behind mlp compute) ----
        short8 af0[7], af1[7];
        if (doConv) {
            const int l0 = 2 * i;
            #pragma unroll
            for (int s = 0; s < 7; s++) {
                af0[s] = *(const short8*)&s_seq[col * SEQ_STRIDE + l0 * CINP + 32 * s + quad * 8];
                af1[s] = *(const short8*)&s_seq[col * SEQ_STRIDE + (l0 + 1) * CINP + 32 * s + quad * 8];
            }
        }

        // ---- MLP for pair i-1 ----
        if (doMlp) {
            const int lm0 = 2 * i - 2, lm1 = 2 * i - 1;
            f32x4 hacc0[2] = {{0.f,0.f,0.f,0.f},{0.f,0.f,0.f,0.f}};
            f32x4 hacc1[2] = {{0.f,0.f,0.f,0.f},{0.f,0.f,0.f,0.f}};
            #pragma unroll
            for (int s = 0; s < 4; s++) {
                hacc0[0] = __builtin_amdgcn_mfma_f32_16x16x32_bf16(am0[s], w1b[0][s], hacc0[0], 0, 0, 0);
                hacc0[1] = __builtin_amdgcn_mfma_f32_16x16x32_bf16(am0[s], w1b[1][s], hacc0[1], 0, 0, 0);
                hacc1[0] = __builtin_amdgcn_mfma_f32_16x16x32_bf16(am1[s], w1b[0][s], hacc1[0], 0, 0, 0);
                hacc1[1] = __builtin_amdgcn_mfma_f32_16x16x32_bf16(am1[s], w1b[1][s], hacc1[1], 0, 0, 0);
            }
            float p0[4], p1[4];
            #pragma unroll
            for (int r = 0; r < 4; r++) {
                p0[r] = fmaxf(hacc0[0][r] + b1v[0], 0.f) * w2v[0]
                      + fmaxf(hacc0[1][r] + b1v[1], 0.f) * w2v[1];
                p1[r] = fmaxf(hacc1[0][r] + b1v[0], 0.f) * w2v[0]
                      + fmaxf(hacc1[1][r] + b1v[1], 0.f) * w2v[1];
            }
            #pragma unroll
            for (int r = 0; r < 4; r++) {
                p0[r] += __shfl_xor(p0[r], 1); p1[r] += __shfl_xor(p1[r], 1);
                p0[r] += __shfl_xor(p0[r], 2); p1[r] += __shfl_xor(p1[r], 2);
                p0[r] += __shfl_xor(p0[r], 4); p1[r] += __shfl_xor(p1[r], 4);
                p0[r] += __shfl_xor(p0[r], 8); p1[r] += __shfl_xor(p1[r], 8);
            }
            if (col == 0) {
                *(f32x4*)&s_yp[lm0][wave][quad * 4] = (f32x4){p0[0], p0[1], p0[2], p0[3]};
                if (lm1 < Ln)
                    *(f32x4*)&s_yp[lm1][wave][quad * 4] = (f32x4){p1[0], p1[1], p1[2], p1[3]};
            }
        }

        // ---- conv for pair i ----
        if (doConv) {
            const int l0 = 2 * i, l1 = l0 + 1;
            f32x4 cacc0[2] = {{0.f,0.f,0.f,0.f},{0.f,0.f,0.f,0.f}};
            f32x4 cacc1[2] = {{0.f,0.f,0.f,0.f},{0.f,0.f,0.f,0.f}};
            #pragma unroll
            for (int s = 0; s < 7; s++) {
                cacc0[0] = __builtin_amdgcn_mfma_f32_16x16x32_bf16(wb[0][s], af0[s], cacc0[0], 0, 0, 0);
                cacc0[1] = __builtin_amdgcn_mfma_f32_16x16x32_bf16(wb[1][s], af0[s], cacc0[1], 0, 0, 0);
                cacc1[0] = __builtin_amdgcn_mfma_f32_16x16x32_bf16(wb[0][s], af1[s], cacc1[0], 0, 0, 0);
                cacc1[1] = __builtin_amdgcn_mfma_f32_16x16x32_bf16(wb[1][s], af1[s], cacc1[1], 0, 0, 0);
            }
            float cm0 = (l0 >= 10 + plen_lane && l0 < 20 + plen_lane) ? 1.0f : 0.0f;
            float cm1 = (l1 >= 10 + plen_lane && l1 < 20 + plen_lane) ? 1.0f : 0.0f;
            #pragma unroll
            for (int tt = 0; tt < 2; tt++) {
                float a0 = fmaxf(cacc0[tt][0] + cbias[tt][0], 0.0f);
                float a1 = fmaxf(cacc0[tt][1] + cbias[tt][1], 0.0f);
                float a2 = fmaxf(cacc0[tt][2] + cbias[tt][2], 0.0f);
                float a3 = fmaxf(cacc0[tt][3] + cbias[tt][3], 0.0f);
                float e0 = fmaxf(cacc1[tt][0] + cbias[tt][0], 0.0f);
                float e1 = fmaxf(cacc1[tt][1] + cbias[tt][1], 0.0f);
                float e2 = fmaxf(cacc1[tt][2] + cbias[tt][2], 0.0f);
                float e3 = fmaxf(cacc1[tt][3] + cbias[tt][3], 0.0f);
                if (l0 < 10) {            // wave-uniform
                    sum_n[tt][0] += a0; sum_n[tt][1] += a1;
                    sum_n[tt][2] += a2; sum_n[tt][3] += a3;
                }
                if (l1 < 10) {
                    sum_n[tt][0] += e0; sum_n[tt][1] += e1;
                    sum_n[tt][2] += e2; sum_n[tt][3] += e3;
                }
                sum_c[tt][0] += cm0 * a0 + cm1 * e0;
                sum_c[tt][1] += cm0 * a1 + cm1 * e1;
                sum_c[tt][2] += cm0 * a2 + cm1 * e2;
                sum_c[tt][3] += cm0 * a3 + cm1 * e3;
                ushort4 pk0 = { bf16bits(a0), bf16bits(a1), bf16bits(a2), bf16bits(a3) };
                ushort4 pk1 = { bf16bits(e0), bf16bits(e1), bf16bits(e2), bf16bits(e3) };
                *(ushort4*)&s_tile[ws_][col * TILE_STRIDE + (2 * wave + tt) * 16 + 4 * quad] = pk0;
                *(ushort4*)&s_tile[ws_][(16 + col) * TILE_STRIDE + (2 * wave + tt) * 16 + 4 * quad] = pk1;
            }
            __syncthreads();   // tile(i) visible for stage i+1's mlp; WAR fence
        }
    }
    __syncthreads();   // all s_seq reads done -> overlay safe; s_yp complete

    // ---- flank-average partials: apply navg_w/cavg_w post-loop ----
    {
        float an = 0.f, ac = 0.f;
        #pragma unroll
        for (int tt = 0; tt < 2; tt++)
            #pragma unroll
            for (int r = 0; r < 4; r++) {
                int fidx = (2 * wave + tt) * 16 + 4 * quad + r;
                an += sum_n[tt][r] * navg_w[fidx];
                ac += sum_c[tt][r] * cavg_w[fidx];
            }
        an += __shfl_xor(an, 16); an += __shfl_xor(an, 32);   // sum over quads
        ac += __shfl_xor(ac, 16); ac += __shfl_xor(ac, 32);
        if (quad == 0) {                     // lane < 16: one per batch
            s_avg[wave * 2 * GB + 0 * GB + col] = an;
            s_avg[wave * 2 * GB + 1 * GB + col] = ac;
        }
    }
    __syncthreads();

    // ---- y finalize: y = tanh(partial_w0 + partial_w1 + b2), 1120 values ----
    {
        const float bn = n_b2[0], bc = c_b2[0];
        for (int i = t; i < 2 * GB * Ln; i += 256) {
            int hd = i / (GB * Ln), rem = i % (GB * Ln);
            int m = rem / Ln, l = rem % Ln;
            float v = s_yp[l][hd * 2][m] + s_yp[l][hd * 2 + 1][m] + (hd ? bc : bn);
            s_y[hd * GB * 36 + m * 36 + l] = tanhf(v);
        }
    }
    __syncthreads();

    // ---- final combine: one thread per batch row ----
    if (t < GB) {
        const int m = t;
        const int plen = plen_arr[b0 + m];
        const float* ym = s_y + m * 36;               // n-head row
        const float* yc = s_y + GB * 36 + m * 36;     // c-head row
        float cleaved_n = ym[10];
        float mn = 0.f;   // reference maxes (y+1)*mask over ALL l; unmasked give 0
        for (int l = 11; l < 10 + plen; l++) mn = fmaxf(mn, ym[l] + 1.f);
        float maxpool_n = -(mn - 1.f);
        float cleaved_c = yc[10 + plen - 1];
        float mc = 0.f;
        for (int l = 10; l < 10 + plen - 1; l++) mc = fmaxf(mc, yc[l] + 1.f);
        float maxpool_c = -(mc - 1.f);
        float sn = 0.f, sc = 0.f;
        #pragma unroll
        for (int w = 0; w < 4; w++) {
            sn += s_avg[w * 2 * GB + 0 * GB + m];
            sc += s_avg[w * 2 * GB + 1 * GB + m];
        }
        float avg_n = tanhf(sn * 0.1f + navg_b[0]);
        float avg_c = tanhf(sc * 0.1f + cavg_b[0]);
        float comb = cleaved_n * out_w[0] + maxpool_n * out_w[1] + avg_n * out_w[2]
                   + cleaved_c * out_w[3] + maxpool_c * out_w[4] + avg_c * out_w[5]
                   + out_b[0];
        out[b0 + m] = 1.f / (1.f + expf(-comb));
    }
}

extern "C" void kernel_launch(void* const* d_in, const int* in_sizes, int n_in,
                              void* d_out, int out_size, void* d_ws, size_t ws_size,
                              hipStream_t stream) {
    const int B = in_sizes[1];
    fused_kernel<<<B / GB, 256, 0, stream>>>(
        (const float*)d_in[0],  (const int*)d_in[1],
        (const float*)d_in[2],  (const float*)d_in[3],
        (const float*)d_in[4],  (const float*)d_in[5],
        (const float*)d_in[6],  (const float*)d_in[7],
        (const float*)d_in[8],  (const float*)d_in[9],
        (const float*)d_in[10], (const float*)d_in[11],
        (const float*)d_in[12], (const float*)d_in[13],
        (const float*)d_in[14], (const float*)d_in[15],
        (const float*)d_in[16], (const float*)d_in[17],
        (float*)d_out);
}

// Round 10
// 418.351 us; speedup vs baseline: 1.2080x; 1.0039x over previous
//
#include <hip/hip_runtime.h>
#include <hip/hip_bf16.h>
#include <math.h>

// Problem constants
#define Ln     35
#define CINn   21
#define CINP   24        // padded CIN (multiple of 8 -> aligned b128 im2col reads)
#define Fn     128
#define Kn     9
#define Hn     64
#define GB     16        // batch rows per block
#define SEQ_STRIDE 1064  // 44 rows*24 + 8 slack (shorts); l=35 window ends at 1064
#define TILE_STRIDE 136  // 128 + 8 pad (shorts)

typedef __attribute__((ext_vector_type(8))) short short8;
typedef __attribute__((ext_vector_type(4))) float f32x4;

static __device__ __forceinline__ unsigned short bf16bits(float f) {
    __hip_bfloat16 h = __float2bfloat16(f);
    return *(unsigned short*)&h;
}

// ---------------- single fused kernel: 16 batch rows / block, 512 threads ----------------
// 8 waves/block; wave w owns conv f-tile [16w,16w+16) and MLP n-tile [16w,16w+16)
// (n<64 = n-head, n>=64 = c-head). Weight frags per wave: 28+16 = 44 VGPRs (half of
// the 4-wave layout) -> working set ~120 regs -> (512,4) = 4 waves/SIMD = 16 waves/CU.
__global__ __launch_bounds__(512, 4) void fused_kernel(
    const float* __restrict__ seq,    const int*   __restrict__ plen_arr,
    const float* __restrict__ conv_w, const float* __restrict__ conv_b,
    const float* __restrict__ n_w1,   const float* __restrict__ n_b1,
    const float* __restrict__ n_w2,   const float* __restrict__ n_b2,
    const float* __restrict__ c_w1,   const float* __restrict__ c_b1,
    const float* __restrict__ c_w2,   const float* __restrict__ c_b2,
    const float* __restrict__ navg_w, const float* __restrict__ navg_b,
    const float* __restrict__ cavg_w, const float* __restrict__ cavg_b,
    const float* __restrict__ out_w,  const float* __restrict__ out_b,
    float* __restrict__ out)
{
    __shared__ __align__(16) unsigned short s_seq[GB * SEQ_STRIDE];      // 34048 B
    __shared__ __align__(16) unsigned short s_tile[4][GB * TILE_STRIDE]; // 17408 B
    __shared__ __align__(16) float s_yp[Ln][8][GB];                      // 17920 B
    // overlays on s_seq (dead after the main loop):
    float* s_y   = (float*)s_seq;            // [2][GB][36] = 1152 floats
    float* s_avg = (float*)s_seq + 1152;     // [8 waves][2][GB] = 256 floats

    const int t    = threadIdx.x;
    const int wave = t >> 6;                 // 0..7
    const int lane = t & 63;
    const int quad = lane >> 4;
    const int col  = lane & 15;
    const int b0   = blockIdx.x * GB;

    // ---- zero-init padded seq (pad rows/channels + slack must be 0) ----
    {
        uint4* p = (uint4*)s_seq;            // 34048/16 = 2128 uint4
        for (int i = t; i < (GB * SEQ_STRIDE) / 8; i += 512)
            p[i] = make_uint4(0u, 0u, 0u, 0u);
    }

    // ---- per-lane loop-invariant weight fragments (single tile per wave) ----
    // conv A-frag (operand-swapped): A[m=f=16*wave+col][k=kk], kk = k*24+c
    // MLP  B-frag: B[k=f][n=16*wave+col]
    short8 wb[7];
    short8 w1b[4];
    float  cbias[4], b1v, w2v;
    const int head = wave >> 2;              // 0 = n-head (waves 0-3), 1 = c (waves 4-7)
    {
        const int ng = wave * 16 + col;      // conv f (A m-index) AND mlp n-index
        #pragma unroll
        for (int s = 0; s < 7; s++) {
            short8 v;
            #pragma unroll
            for (int j = 0; j < 8; j++) {
                int kk = 32 * s + quad * 8 + j;
                int k = kk / CINP, c = kk % CINP;
                float f = (k < Kn && c < CINn) ? conv_w[(k * CINn + c) * Fn + ng] : 0.0f;
                v[j] = (short)bf16bits(f);
            }
            wb[s] = v;
        }
        const int nl = ng & 63;
        #pragma unroll
        for (int s = 0; s < 4; s++) {
            short8 v;
            #pragma unroll
            for (int j = 0; j < 8; j++) {
                int k = 32 * s + quad * 8 + j;
                float f = head ? c_w1[k * Hn + nl] : n_w1[k * Hn + nl];
                v[j] = (short)bf16bits(f);
            }
            w1b[s] = v;
        }
        #pragma unroll
        for (int r = 0; r < 4; r++)
            cbias[r] = conv_b[wave * 16 + 4 * quad + r];
        b1v = head ? c_b1[nl] : n_b1[nl];
        w2v = head ? c_w2[nl] : n_w2[nl];
    }
    const int plen_lane = plen_arr[b0 + col];   // this lane's batch (=col) plen

    __syncthreads();   // zero-init done before data fill

    // ---- stage seq -> bf16 LDS, rows shifted +4 (SAME pad), c<21 only ----
    for (int i = t; i < GB * Ln * CINn; i += 512) {
        int bi = i / (Ln * CINn), r = i % (Ln * CINn);
        int l = r / CINn, c = r % CINn;
        s_seq[bi * SEQ_STRIDE + (4 + l) * CINP + c] =
            bf16bits(seq[(size_t)(b0 + bi) * (Ln * CINn) + r]);
    }
    __syncthreads();

    float sum_n[4] = {0.f,0.f,0.f,0.f};
    float sum_c[4] = {0.f,0.f,0.f,0.f};

    // ---- main loop: 2 l per stage, 18 stages, 1 barrier each. 4-slot ring:
    // stage i writes slots {2i&3,(2i+1)&3}; WAR on a slot is fenced 1 stage later.
    // l=35 is a computed pad column (auto-masked from sums; y-write guarded).
    for (int l0 = 0; l0 < 36; l0 += 2) {
        const int l1 = l0 + 1;
        // ---- conv GEMM (operand-swapped): D^T[f][batch], wave's 16-f tile ----
        short8 af0[7], af1[7];
        #pragma unroll
        for (int s = 0; s < 7; s++) {
            af0[s] = *(const short8*)&s_seq[col * SEQ_STRIDE + l0 * CINP + 32 * s + quad * 8];
            af1[s] = *(const short8*)&s_seq[col * SEQ_STRIDE + l1 * CINP + 32 * s + quad * 8];
        }
        f32x4 cacc0 = {0.f,0.f,0.f,0.f};
        f32x4 cacc1 = {0.f,0.f,0.f,0.f};
        #pragma unroll
        for (int s = 0; s < 7; s++) {
            cacc0 = __builtin_amdgcn_mfma_f32_16x16x32_bf16(wb[s], af0[s], cacc0, 0, 0, 0);
            cacc1 = __builtin_amdgcn_mfma_f32_16x16x32_bf16(wb[s], af1[s], cacc1, 0, 0, 0);
        }
        // ---- epilogue: lane holds batch=col, f = 16*wave + 4q + r ----
        {
            float cm0 = (l0 >= 10 + plen_lane && l0 < 20 + plen_lane) ? 1.0f : 0.0f;
            float cm1 = (l1 >= 10 + plen_lane && l1 < 20 + plen_lane) ? 1.0f : 0.0f;
            float a0 = fmaxf(cacc0[0] + cbias[0], 0.0f);
            float a1 = fmaxf(cacc0[1] + cbias[1], 0.0f);
            float a2 = fmaxf(cacc0[2] + cbias[2], 0.0f);
            float a3 = fmaxf(cacc0[3] + cbias[3], 0.0f);
            float e0 = fmaxf(cacc1[0] + cbias[0], 0.0f);
            float e1 = fmaxf(cacc1[1] + cbias[1], 0.0f);
            float e2 = fmaxf(cacc1[2] + cbias[2], 0.0f);
            float e3 = fmaxf(cacc1[3] + cbias[3], 0.0f);
            if (l0 < 10) {            // wave-uniform
                sum_n[0] += a0; sum_n[1] += a1; sum_n[2] += a2; sum_n[3] += a3;
            }
            if (l1 < 10) {
                sum_n[0] += e0; sum_n[1] += e1; sum_n[2] += e2; sum_n[3] += e3;
            }
            sum_c[0] += cm0 * a0 + cm1 * e0;
            sum_c[1] += cm0 * a1 + cm1 * e1;
            sum_c[2] += cm0 * a2 + cm1 * e2;
            sum_c[3] += cm0 * a3 + cm1 * e3;
            ushort4 pk0 = { bf16bits(a0), bf16bits(a1), bf16bits(a2), bf16bits(a3) };
            ushort4 pk1 = { bf16bits(e0), bf16bits(e1), bf16bits(e2), bf16bits(e3) };
            *(ushort4*)&s_tile[l0 & 3][col * TILE_STRIDE + wave * 16 + 4 * quad] = pk0;
            *(ushort4*)&s_tile[l1 & 3][col * TILE_STRIDE + wave * 16 + 4 * quad] = pk1;
        }
        __syncthreads();   // conv tiles written -> MLP may read; WAR fence for ring

        // ---- MLP layer1 GEMM: D[m=batch][n = wave's 16-n tile], K = 128 f ----
        short8 am0[4], am1[4];
        #pragma unroll
        for (int s = 0; s < 4; s++) {
            am0[s] = *(const short8*)&s_tile[l0 & 3][col * TILE_STRIDE + 32 * s + quad * 8];
            am1[s] = *(const short8*)&s_tile[l1 & 3][col * TILE_STRIDE + 32 * s + quad * 8];
        }
        f32x4 hacc0 = {0.f,0.f,0.f,0.f};
        f32x4 hacc1 = {0.f,0.f,0.f,0.f};
        #pragma unroll
        for (int s = 0; s < 4; s++) {
            hacc0 = __builtin_amdgcn_mfma_f32_16x16x32_bf16(am0[s], w1b[s], hacc0, 0, 0, 0);
            hacc1 = __builtin_amdgcn_mfma_f32_16x16x32_bf16(am1[s], w1b[s], hacc1, 0, 0, 0);
        }
        // ---- y partial = relu(h+b1) @ w2 over this wave's 16 n; reduce cols ----
        float p0[4], p1[4];
        #pragma unroll
        for (int r = 0; r < 4; r++) {
            p0[r] = fmaxf(hacc0[r] + b1v, 0.f) * w2v;
            p1[r] = fmaxf(hacc1[r] + b1v, 0.f) * w2v;
        }
        #pragma unroll
        for (int r = 0; r < 4; r++) {
            p0[r] += __shfl_xor(p0[r], 1); p1[r] += __shfl_xor(p1[r], 1);
            p0[r] += __shfl_xor(p0[r], 2); p1[r] += __shfl_xor(p1[r], 2);
            p0[r] += __shfl_xor(p0[r], 4); p1[r] += __shfl_xor(p1[r], 4);
            p0[r] += __shfl_xor(p0[r], 8); p1[r] += __shfl_xor(p1[r], 8);
        }
        if (col == 0) {
            *(f32x4*)&s_yp[l0][wave][quad * 4] = (f32x4){p0[0], p0[1], p0[2], p0[3]};
            if (l1 < Ln)
                *(f32x4*)&s_yp[l1][wave][quad * 4] = (f32x4){p1[0], p1[1], p1[2], p1[3]};
        }
    }
    __syncthreads();   // all s_seq reads done -> overlay safe; s_yp complete

    // ---- flank-average partials: apply navg_w/cavg_w post-loop ----
    {
        float an = 0.f, ac = 0.f;
        #pragma unroll
        for (int r = 0; r < 4; r++) {
            int fidx = wave * 16 + 4 * quad + r;
            an += sum_n[r] * navg_w[fidx];
            ac += sum_c[r] * cavg_w[fidx];
        }
        an += __shfl_xor(an, 16); an += __shfl_xor(an, 32);   // sum over quads
        ac += __shfl_xor(ac, 16); ac += __shfl_xor(ac, 32);
        if (quad == 0) {                     // lane < 16: one per batch
            s_avg[wave * 2 * GB + 0 * GB + col] = an;
            s_avg[wave * 2 * GB + 1 * GB + col] = ac;
        }
    }
    __syncthreads();

    // ---- y finalize: y = tanh(sum of 4 wave-partials + b2), 1120 values ----
    {
        const float bn = n_b2[0], bc = c_b2[0];
        for (int i = t; i < 2 * GB * Ln; i += 512) {
            int hd = i / (GB * Ln), rem = i % (GB * Ln);
            int m = rem / Ln, l = rem % Ln;
            float v = (hd ? bc : bn);
            #pragma unroll
            for (int w = 0; w < 4; w++)
                v += s_yp[l][hd * 4 + w][m];
            s_y[hd * GB * 36 + m * 36 + l] = tanhf(v);
        }
    }
    __syncthreads();

    // ---- final combine: one thread per batch row ----
    if (t < GB) {
        const int m = t;
        const int plen = plen_arr[b0 + m];
        const float* ym = s_y + m * 36;               // n-head row
        const float* yc = s_y + GB * 36 + m * 36;     // c-head row
        float cleaved_n = ym[10];
        float mn = 0.f;   // reference maxes (y+1)*mask over ALL l; unmasked give 0
        for (int l = 11; l < 10 + plen; l++) mn = fmaxf(mn, ym[l] + 1.f);
        float maxpool_n = -(mn - 1.f);
        float cleaved_c = yc[10 + plen - 1];
        float mc = 0.f;
        for (int l = 10; l < 10 + plen - 1; l++) mc = fmaxf(mc, yc[l] + 1.f);
        float maxpool_c = -(mc - 1.f);
        float sn = 0.f, sc = 0.f;
        #pragma unroll
        for (int w = 0; w < 8; w++) {
            sn += s_avg[w * 2 * GB + 0 * GB + m];
            sc += s_avg[w * 2 * GB + 1 * GB + m];
        }
        float avg_n = tanhf(sn * 0.1f + navg_b[0]);
        float avg_c = tanhf(sc * 0.1f + cavg_b[0]);
        float comb = cleaved_n * out_w[0] + maxpool_n * out_w[1] + avg_n * out_w[2]
                   + cleaved_c * out_w[3] + maxpool_c * out_w[4] + avg_c * out_w[5]
                   + out_b[0];
        out[b0 + m] = 1.f / (1.f + expf(-comb));
    }
}

extern "C" void kernel_launch(void* const* d_in, const int* in_sizes, int n_in,
                              void* d_out, int out_size, void* d_ws, size_t ws_size,
                              hipStream_t stream) {
    const int B = in_sizes[1];
    fused_kernel<<<B / GB, 512, 0, stream>>>(
        (const float*)d_in[0],  (const int*)d_in[1],
        (const float*)d_in[2],  (const float*)d_in[3],
        (const float*)d_in[4],  (const float*)d_in[5],
        (const float*)d_in[6],  (const float*)d_in[7],
        (const float*)d_in[8],  (const float*)d_in[9],
        (const float*)d_in[10], (const float*)d_in[11],
        (const float*)d_in[12], (const float*)d_in[13],
        (const float*)d_in[14], (const float*)d_in[15],
        (const float*)d_in[16], (const float*)d_in[17],
        (float*)d_out);
}